// Round 18
// baseline (313.239 us; speedup 1.0000x reference)
//
#include <hip/hip_runtime.h>
#include <hip/hip_bf16.h>
#include <math.h>

// Problem constants
#define MTOK   8192   // B*L
#define LSEQ   2048
#define NBATCH 4
#define DMODEL 1024
#define DINNER 2048
#define DSTATE 16
#define DTRANK 64
#define NXZ    4096
#define CHUNK  64
#define NCH    32     // LSEQ / CHUNK
#define NPROJ  (MTOK * 96)
#define SPLITK 4

typedef _Float16 f16;
using f16x8 = __attribute__((ext_vector_type(8))) _Float16;
using f16x4 = __attribute__((ext_vector_type(4))) _Float16;
using f32x4 = __attribute__((ext_vector_type(4))) float;

__device__ __forceinline__ float silu_f(float x) { return x / (1.f + __expf(-x)); }

// async global->LDS, 16B per lane; lds dest = wave-uniform base + lane*16B
__device__ __forceinline__ void gload_lds16(const void* g, void* l) {
    __builtin_amdgcn_global_load_lds(
        (const __attribute__((address_space(1))) void*)g,
        (__attribute__((address_space(3))) void*)l, 16, 0, 0);
}

// ---------------------------------------------------------------------------
// f32 -> f16 elementwise (vec4)
// ---------------------------------------------------------------------------
__global__ __launch_bounds__(256)
void cvt_f2h(const float* __restrict__ in, f16* __restrict__ out, int n4)
{
    const int i = blockIdx.x * 256 + threadIdx.x;
    if (i >= n4) return;
    const float4 v = ((const float4*)in)[i];
    f16x4 o;
    o[0] = (f16)v.x; o[1] = (f16)v.y; o[2] = (f16)v.z; o[3] = (f16)v.w;
    ((f16x4*)out)[i] = o;
}

// ---------------------------------------------------------------------------
// Transpose + convert body: in f32 [R][C] -> out f16 [C][R], 32x32 tile.
// ---------------------------------------------------------------------------
__device__ __forceinline__ void tcvt_body(const float* __restrict__ in,
                                          f16* __restrict__ out,
                                          int R, int C, int bx, int by)
{
    __shared__ float t[32][33];
    const int c0 = bx * 32, r0 = by * 32;
    const int tx = threadIdx.x & 31, ty = threadIdx.x >> 5;   // 32 x 8
    #pragma unroll
    for (int j = 0; j < 4; ++j)
        t[ty + 8 * j][tx] = in[(size_t)(r0 + ty + 8 * j) * C + c0 + tx];
    __syncthreads();
    #pragma unroll
    for (int j = 0; j < 4; ++j)
        out[(size_t)(c0 + ty + 8 * j) * R + r0 + tx] = (f16)t[tx][ty + 8 * j];
}

__global__ __launch_bounds__(256)
void tcvt(const float* __restrict__ in, f16* __restrict__ out, int R, int C)
{
    tcvt_body(in, out, R, C, blockIdx.x, blockIdx.y);
}

// Batched transpose of the three small weights in one dispatch.
// blocks: [0,192) Wxp (96x? grid 3x64), [192,320) Wdt (64x2), [320,2368) Wout.
__global__ __launch_bounds__(256)
void tcvt3(const float* __restrict__ W_xp, f16* __restrict__ WxpT,
           const float* __restrict__ W_dt, f16* __restrict__ WdtT,
           const float* __restrict__ W_out, f16* __restrict__ WoutT)
{
    int id = blockIdx.x;
    if (id < 192) {
        tcvt_body(W_xp, WxpT, DINNER, 96, id % 3, id / 3);
    } else if (id < 320) {
        id -= 192;
        tcvt_body(W_dt, WdtT, DTRANK, DINNER, id % 64, id / 64);
    } else {
        id -= 320;
        tcvt_body(W_out, WoutT, DINNER, DMODEL, id % 32, id / 32);
    }
}

// ---------------------------------------------------------------------------
// 256x256 8-phase deep-pipelined FP16 GEMM (m201 template, T2+T3+T4+T5).
// 3-bit G4 swizzle, counted vmcnt, conflict-free.  See round-15/16 headers.
// ---------------------------------------------------------------------------
__global__ __launch_bounds__(512, 1)
void hgemm256p(const f16* __restrict__ A, int lda,
               const f16* __restrict__ Bt, int ldb,
               f16* __restrict__ C, int ldc,
               int K, f16* __restrict__ C2, int splitcol)
{
    __shared__ __align__(16) f16 SA[2][16384];
    __shared__ __align__(16) f16 SB[2][16384];

    const int tid  = threadIdx.x;
    const int lane = tid & 63, w = tid >> 6;
    const int wr = w >> 2, wc = w & 3;            // 2 x 4 wave grid
    const int row0 = blockIdx.x * 256;
    int col0 = blockIdx.y * 256;

    const int frow = lane & 15;
    const int nt = K / 64;

    auto issue_half = [&](int q) {
        const int t = q >> 2, j = q & 3, buf = t & 1, k0 = t * 64;
        const bool isA = (j >= 2);
        const int hh = j & 1;
        const f16* base = isA ? (A  + (size_t)(row0 + hh * 128) * lda + k0)
                              : (Bt + (size_t)(col0 + hh * 128) * ldb + k0);
        const int ld = isA ? lda : ldb;
        f16* dst = (isA ? &SA[buf][0] : &SB[buf][0]) + hh * 8192;
        #pragma unroll
        for (int r2 = 0; r2 < 2; ++r2) {
            const int ch = r2 * 512 + tid;        // 16B unit index
            const int grow  = ch >> 3;            // row 0..127
            const int gunit = (ch & 7) ^ (grow & 7);   // inverse swizzle
            gload_lds16(base + (size_t)grow * ld + gunit * 8, dst + ch * 8);
        }
    };

    int next = 0;
    for (; next < 6 && next < 4 * nt; ++next) issue_half(next);
    asm volatile("s_waitcnt vmcnt(4)" ::: "memory");
    asm volatile("s_barrier" ::: "memory");

    f32x4 acc[8][4] = {};

    for (int t = 0; t < nt; ++t) {
        const int buf = t & 1;
        const char* Ab = (const char*)&SA[buf][0];
        const char* Bb = (const char*)&SB[buf][0];
        f16x8 bf[4][2];
        #pragma unroll
        for (int p = 0; p < 4; ++p) {
            f16x8 af[2][2];
            if (p == 0) {
                #pragma unroll
                for (int n = 0; n < 4; ++n)
                    #pragma unroll
                    for (int ks = 0; ks < 2; ++ks) {
                        const int R = wc * 64 + n * 16 + frow;
                        const int off = R * 128 +
                            ((ks * 64 + (lane >> 4) * 16) ^ ((R & 7) << 4));
                        bf[n][ks] = *(const f16x8*)(Bb + off);
                    }
            }
            #pragma unroll
            for (int i = 0; i < 2; ++i)
                #pragma unroll
                for (int ks = 0; ks < 2; ++ks) {
                    const int R = wr * 128 + (2 * p + i) * 16 + frow;
                    const int off = R * 128 +
                        ((ks * 64 + (lane >> 4) * 16) ^ ((R & 7) << 4));
                    af[i][ks] = *(const f16x8*)(Ab + off);
                }
            if (next < 4 * nt) issue_half(next++);
            asm volatile("s_barrier" ::: "memory");
            asm volatile("s_waitcnt lgkmcnt(0)" ::: "memory");
            __builtin_amdgcn_sched_barrier(0);
            __builtin_amdgcn_s_setprio(1);
            #pragma unroll
            for (int i = 0; i < 2; ++i)
                #pragma unroll
                for (int n = 0; n < 4; ++n)
                    #pragma unroll
                    for (int ks = 0; ks < 2; ++ks)
                        acc[2 * p + i][n] = __builtin_amdgcn_mfma_f32_16x16x32_f16(
                            af[i][ks], bf[n][ks], acc[2 * p + i][n], 0, 0, 0);
            __builtin_amdgcn_s_setprio(0);
            if (p == 3 && t + 1 < nt) {
                if (next >= 4 * t + 10) asm volatile("s_waitcnt vmcnt(4)" ::: "memory");
                else                    asm volatile("s_waitcnt vmcnt(0)" ::: "memory");
            }
            asm volatile("s_barrier" ::: "memory");
        }
    }

    f16* Cw = C;
    if (C2 != nullptr && col0 >= splitcol) { Cw = C2; col0 -= splitcol; }

    const int rbase = row0 + wr * 128 + (lane >> 4) * 4;
    const int cbase = col0 + wc * 64 + (lane & 15);
    #pragma unroll
    for (int m = 0; m < 8; ++m) {
        #pragma unroll
        for (int n = 0; n < 4; ++n) {
            const int col = cbase + n * 16;
            #pragma unroll
            for (int r = 0; r < 4; ++r)
                Cw[(size_t)(rbase + m * 16 + r) * ldc + col] = (f16)acc[m][n][r];
        }
    }
}

// ---------------------------------------------------------------------------
// FP16 MFMA GEMM, m97 double-buffer + XOR unit-swizzle (T2, both sides).
// Used for the out GEMM.
// ---------------------------------------------------------------------------
template<int EPI, typename OUT_T>
__global__ __launch_bounds__(256)
void hgemm128(const f16* __restrict__ A, int lda,
              const f16* __restrict__ Bt, int ldb,
              OUT_T* __restrict__ C, int ldc,
              int K, const float* __restrict__ bias,
              OUT_T* __restrict__ C2, int splitcol)
{
    __shared__ __align__(16) f16 As[2][128 * 32];
    __shared__ __align__(16) f16 Bs[2][128 * 32];

    const int tid  = threadIdx.x;
    const int lane = tid & 63, wave = tid >> 6;
    const int wr = wave >> 1, wc = wave & 1;
    const int row0 = blockIdx.x * 128;
    int col0 = blockIdx.y * 128;

    const int lrow = lane >> 2;
    const int lcol = ((lane & 3) ^ ((lane >> 3) & 3)) * 8;
    const f16* Agw = A  + (size_t)(row0 + wave * 32 + lrow) * lda + lcol;
    const f16* Bgw = Bt + (size_t)(col0 + wave * 32 + lrow) * ldb + lcol;
    const int ldsbase = (wave * 32) * 32;   // elems

    const int frow = lane & 15;
    const int fk   = (((lane >> 4) ^ ((frow >> 1) & 3))) * 8;
    const int nt = K / 32;

    f32x4 acc[4][4] = {};

    #pragma unroll
    for (int r = 0; r < 2; ++r) {
        gload_lds16(Agw + (size_t)r * 16 * lda, &As[0][ldsbase + r * 16 * 32]);
        gload_lds16(Bgw + (size_t)r * 16 * ldb, &Bs[0][ldsbase + r * 16 * 32]);
    }

    int cur = 0;
    for (int kt = 0; kt < nt; ++kt) {
        __syncthreads();
        if (kt + 1 < nt) {
            const int k0 = (kt + 1) * 32;
            #pragma unroll
            for (int r = 0; r < 2; ++r) {
                gload_lds16(Agw + (size_t)r * 16 * lda + k0, &As[cur ^ 1][ldsbase + r * 16 * 32]);
                gload_lds16(Bgw + (size_t)r * 16 * ldb + k0, &Bs[cur ^ 1][ldsbase + r * 16 * 32]);
            }
        }
        f16x8 af[4], bf[4];
        #pragma unroll
        for (int m = 0; m < 4; ++m)
            af[m] = *(const f16x8*)&As[cur][(wr * 64 + m * 16 + frow) * 32 + fk];
        #pragma unroll
        for (int n = 0; n < 4; ++n)
            bf[n] = *(const f16x8*)&Bs[cur][(wc * 64 + n * 16 + frow) * 32 + fk];
        #pragma unroll
        for (int m = 0; m < 4; ++m)
            #pragma unroll
            for (int n = 0; n < 4; ++n)
                acc[m][n] = __builtin_amdgcn_mfma_f32_16x16x32_f16(af[m], bf[n], acc[m][n], 0, 0, 0);
        cur ^= 1;
    }

    OUT_T* Cw = C;
    if (C2 != nullptr && col0 >= splitcol) { Cw = C2; col0 -= splitcol; }

    const int rbase = row0 + wr * 64 + (lane >> 4) * 4;
    const int cbase = col0 + wc * 64 + (lane & 15);
    #pragma unroll
    for (int m = 0; m < 4; ++m) {
        #pragma unroll
        for (int n = 0; n < 4; ++n) {
            const int col = cbase + n * 16;
            #pragma unroll
            for (int r = 0; r < 4; ++r) {
                const int row = rbase + m * 16 + r;
                float tv = acc[m][n][r];
                if (EPI == 1) {
                    tv += bias[col];
                    tv = (tv > 20.f) ? tv : __logf(1.f + __expf(tv));
                }
                Cw[(size_t)row * ldc + col] = (OUT_T)tv;
            }
        }
    }
}

// ---------------------------------------------------------------------------
// FUSED: delta = softplus(projh[:, :64] @ WdtT^T + b_dt)  +  scan pass1.
// Tile 128 tokens x 128 d == 2 chunks x 128 channels.  After the (K=64) GEMM,
// delta goes to global (pass3 needs it) AND to a swizzled LDS tile (aliased
// over the dead GEMM buffers); threads remap to (chunk, d) and run the
// 64-step S/sum_dt recursion with dt from LDS, u coalesced from global,
// B rows from an 8 KB LDS stage.  LDS 40 KB -> 4 blocks/CU.
// dlt swizzle: col ^= ((row>>2)&3)<<4  (write frag-groups and column reads
// both spread over 32 banks; involution).
// ---------------------------------------------------------------------------
__global__ __launch_bounds__(256)
void delta_scan1(const f16* __restrict__ A,     // projh [MTOK][96]
                 const f16* __restrict__ Bt,    // WdtT [DINNER][64]
                 f16* __restrict__ deltah,      // [MTOK][DINNER]
                 const float* __restrict__ bias,
                 const f16* __restrict__ uh,
                 const float* __restrict__ proj, // B rows (cols 64..79)
                 const float* __restrict__ A_log,
                 f16* __restrict__ Sbufh, float* __restrict__ sumdt)
{
    __shared__ __align__(16) f16 smem[16384];   // 32 KB: GEMM bufs, then dlt
    __shared__ float Bsh[128][16];              // 8 KB
    f16* As = smem;                             // As[2][4096]
    f16* Bs = smem + 8192;                      // Bs[2][4096]

    const int tid  = threadIdx.x;
    const int lane = tid & 63, wave = tid >> 6;
    const int wr = wave >> 1, wc = wave & 1;
    const int row0 = blockIdx.x * 128;          // token base
    const int col0 = blockIdx.y * 128;          // d base

    const int lrow = lane >> 2;
    const int lcol = ((lane & 3) ^ ((lane >> 3) & 3)) * 8;
    const f16* Agw = A  + (size_t)(row0 + wave * 32 + lrow) * 96 + lcol;
    const f16* Bgw = Bt + (size_t)(col0 + wave * 32 + lrow) * 64 + lcol;
    const int ldsbase = (wave * 32) * 32;

    const int frow = lane & 15;
    const int fk   = (((lane >> 4) ^ ((frow >> 1) & 3))) * 8;

    f32x4 acc[4][4] = {};

    #pragma unroll
    for (int r = 0; r < 2; ++r) {
        gload_lds16(Agw + (size_t)r * 16 * 96, &As[ldsbase + r * 16 * 32]);
        gload_lds16(Bgw + (size_t)r * 16 * 64, &Bs[ldsbase + r * 16 * 32]);
    }

    int cur = 0;
    #pragma unroll
    for (int kt = 0; kt < 2; ++kt) {            // K = 64, BK = 32
        __syncthreads();
        if (kt == 0) {
            #pragma unroll
            for (int r = 0; r < 2; ++r) {
                gload_lds16(Agw + (size_t)r * 16 * 96 + 32, &As[4096 + ldsbase + r * 16 * 32]);
                gload_lds16(Bgw + (size_t)r * 16 * 64 + 32, &Bs[4096 + ldsbase + r * 16 * 32]);
            }
        }
        f16x8 af[4], bf[4];
        #pragma unroll
        for (int m = 0; m < 4; ++m)
            af[m] = *(const f16x8*)&As[cur * 4096 + (wr * 64 + m * 16 + frow) * 32 + fk];
        #pragma unroll
        for (int n = 0; n < 4; ++n)
            bf[n] = *(const f16x8*)&Bs[cur * 4096 + (wc * 64 + n * 16 + frow) * 32 + fk];
        #pragma unroll
        for (int m = 0; m < 4; ++m)
            #pragma unroll
            for (int n = 0; n < 4; ++n)
                acc[m][n] = __builtin_amdgcn_mfma_f32_16x16x32_f16(af[m], bf[n], acc[m][n], 0, 0, 0);
        cur ^= 1;
    }

    __syncthreads();                            // all frag reads done; reuse smem
    f16* dlt = smem;                            // [128 tokens][128 d], swizzled

    // epilogue: softplus, write global deltah + swizzled dlt
    const int rloc0 = wr * 64 + (lane >> 4) * 4;
    const int cloc0 = wc * 64 + (lane & 15);
    #pragma unroll
    for (int m = 0; m < 4; ++m) {
        #pragma unroll
        for (int n = 0; n < 4; ++n) {
            const int cl = cloc0 + n * 16;
            #pragma unroll
            for (int r = 0; r < 4; ++r) {
                const int rl = rloc0 + m * 16 + r;
                float tv = acc[m][n][r] + bias[col0 + cl];
                tv = (tv > 20.f) ? tv : __logf(1.f + __expf(tv));
                const f16 hv = (f16)tv;
                deltah[(size_t)(row0 + rl) * DINNER + col0 + cl] = hv;
                dlt[rl * 128 + (cl ^ (((rl >> 2) & 3) << 4))] = hv;
            }
        }
    }

    // stage B rows: proj[row0 + t][64 + c], 128 x 16 f32
    #pragma unroll
    for (int i = 0; i < 8; ++i) {
        const int f = i * 256 + tid;
        Bsh[f >> 4][f & 15] = proj[(size_t)(row0 + (f >> 4)) * 96 + 64 + (f & 15)];
    }
    __syncthreads();

    // scan: thread -> (chunk cl2 in {0,1}, d_local dl in 0..127)
    const int cl2 = tid >> 7, dl = tid & 127;
    const int d = col0 + dl;
    const int b = row0 >> 11;                          // / LSEQ
    const int cb = ((row0 & (LSEQ - 1)) >> 6) + cl2;   // chunk in batch
    const size_t tok0 = (size_t)row0 + cl2 * 64;

    float Av[DSTATE];
    #pragma unroll
    for (int n = 0; n < DSTATE; ++n)
        Av[n] = -__expf(A_log[(size_t)d * DSTATE + n]);
    bool pw = true;
    #pragma unroll
    for (int n = 1; n < DSTATE; ++n)
        if (fabsf(Av[n] / Av[0] - (float)(n + 1)) > 1e-3f) pw = false;
    const float Av0 = Av[0];

    float S[DSTATE];
    #pragma unroll
    for (int n = 0; n < DSTATE; ++n) S[n] = 0.f;
    float sdt = 0.f;

    for (int l = 0; l < CHUNK; ++l) {
        const int rl = cl2 * 64 + l;
        const float dt = (float)dlt[rl * 128 + (dl ^ (((rl >> 2) & 3) << 4))];
        const float uu = (float)uh[(tok0 + l) * DINNER + d];
        sdt += dt;
        const float du = dt * uu;
        if (pw) {
            const float p1 = __expf(dt * Av0);
            const float p2 = p1 * p1;
            const float p3 = p2 * p1;
            const float p4 = p2 * p2;
            float mm = 1.f;
            #pragma unroll
            for (int g = 0; g < 4; ++g) {
                const f32x4 bb = *(const f32x4*)&Bsh[rl][g * 4];
                S[g*4+0] = fmaf(S[g*4+0], mm * p1, du * bb[0]);
                S[g*4+1] = fmaf(S[g*4+1], mm * p2, du * bb[1]);
                S[g*4+2] = fmaf(S[g*4+2], mm * p3, du * bb[2]);
                S[g*4+3] = fmaf(S[g*4+3], mm * p4, du * bb[3]);
                mm *= p4;
            }
        } else {
            #pragma unroll
            for (int n = 0; n < DSTATE; ++n)
                S[n] = fmaf(S[n], __expf(dt * Av[n]), du * Bsh[rl][n]);
        }
    }

    const size_t base = (size_t)b * NCH + cb;
    #pragma unroll
    for (int n = 0; n < DSTATE; ++n)
        Sbufh[(base * DSTATE + n) * DINNER + d] = (f16)S[n];
    sumdt[base * DINNER + d] = sdt;
}

// ---------------------------------------------------------------------------
// Narrow-N GEMM for proj: part[sk] = uh[rows][kseg] @ WxpT^T, N=96, split-K=4.
// ---------------------------------------------------------------------------
__global__ __launch_bounds__(256)
void hgemm_n96(const f16* __restrict__ A,      // uh [MTOK][DINNER]
               const f16* __restrict__ Bt,     // WxpT [96][DINNER]
               float* __restrict__ part)       // [SPLITK][MTOK][96]
{
    __shared__ __align__(16) f16 As[128][40];
    __shared__ __align__(16) f16 Bs[96][40];

    const int tid = threadIdx.x, lane = tid & 63, wave = tid >> 6;
    const int row0 = blockIdx.x * 128;
    const int sk = blockIdx.y;
    const int kbase = sk * (DINNER / SPLITK);   // 512

    const int srow = tid >> 1, skoff = (tid & 1) * 16;
    const f16* Ag = A  + (size_t)(row0 + srow) * DINNER + kbase + skoff;
    const f16* Bg = Bt + (size_t)srow * DINNER + kbase + skoff;

    const int frow = lane & 15, fk = (lane >> 4) * 8;

    f32x4 acc[2][6] = {};

    for (int kk = 0; kk < DINNER / SPLITK; kk += 32) {
        const f16x8 a0 = *(const f16x8*)(Ag + kk);
        const f16x8 a1 = *(const f16x8*)(Ag + kk + 8);
        f16x8 b0 = {}, b1 = {};
        if (tid < 192) { b0 = *(const f16x8*)(Bg + kk); b1 = *(const f16x8*)(Bg + kk + 8); }
        __syncthreads();
        *(f16x8*)&As[srow][skoff]     = a0;
        *(f16x8*)&As[srow][skoff + 8] = a1;
        if (tid < 192) {
            *(f16x8*)&Bs[srow][skoff]     = b0;
            *(f16x8*)&Bs[srow][skoff + 8] = b1;
        }
        __syncthreads();

        f16x8 af[2], bf[6];
        #pragma unroll
        for (int m = 0; m < 2; ++m)
            af[m] = *(const f16x8*)&As[wave * 32 + m * 16 + frow][fk];
        #pragma unroll
        for (int n = 0; n < 6; ++n)
            bf[n] = *(const f16x8*)&Bs[n * 16 + frow][fk];
        #pragma unroll
        for (int m = 0; m < 2; ++m)
            #pragma unroll
            for (int n = 0; n < 6; ++n)
                acc[m][n] = __builtin_amdgcn_mfma_f32_16x16x32_f16(af[m], bf[n], acc[m][n], 0, 0, 0);
    }

    #pragma unroll
    for (int m = 0; m < 2; ++m)
        #pragma unroll
        for (int n = 0; n < 6; ++n) {
            const int col = n * 16 + (lane & 15);
            #pragma unroll
            for (int r = 0; r < 4; ++r) {
                const int row = row0 + wave * 32 + m * 16 + (lane >> 4) * 4 + r;
                part[((size_t)sk * MTOK + row) * 96 + col] = acc[m][n][r];
            }
        }
}

__global__ __launch_bounds__(256)
void reduce3(const float* __restrict__ part, float* __restrict__ proj,
             f16* __restrict__ projh)
{
    const int e = blockIdx.x * 256 + threadIdx.x;   // < NPROJ
    float s = 0.f;
    #pragma unroll
    for (int i = 0; i < SPLITK; ++i) s += part[(size_t)i * NPROJ + e];
    proj[e]  = s;
    projh[e] = (f16)s;
}

// ---------------------------------------------------------------------------
// Causal depthwise conv (D_CONV=4) + bias + SiLU, sliding-window.
// ---------------------------------------------------------------------------
__global__ __launch_bounds__(256)
void conv_silu_kernel(const f16* __restrict__ uph,
                      const float* __restrict__ cw, const float* __restrict__ cb,
                      f16* __restrict__ uh)
{
    const int mt  = blockIdx.x;          // 0 .. MTOK/8-1
    const int ml0 = mt * 8;
    const int l0  = ml0 & (LSEQ - 1);
    const int d   = threadIdx.x * 8;

    float w[8][4];
    #pragma unroll
    for (int c = 0; c < 8; ++c) {
        const float4 wv = *(const float4*)(cw + (size_t)(d + c) * 4);
        w[c][0] = wv.x; w[c][1] = wv.y; w[c][2] = wv.z; w[c][3] = wv.w;
    }
    float bias[8];
    {
        const float4 b0 = *(const float4*)(cb + d);
        const float4 b1 = *(const float4*)(cb + d + 4);
        bias[0] = b0.x; bias[1] = b0.y; bias[2] = b0.z; bias[3] = b0.w;
        bias[4] = b1.x; bias[5] = b1.y; bias[6] = b1.z; bias[7] = b1.w;
    }

    f16x8 r[11];
    if (l0 != 0) {
        #pragma unroll
        for (int i = 0; i < 11; ++i)
            r[i] = *(const f16x8*)(uph + (size_t)(ml0 - 3 + i) * DINNER + d);
    } else {
        r[0] = f16x8{}; r[1] = f16x8{}; r[2] = f16x8{};
        #pragma unroll
        for (int i = 3; i < 11; ++i)
            r[i] = *(const f16x8*)(uph + (size_t)(ml0 - 3 + i) * DINNER + d);
    }

    #pragma unroll
    for (int i = 0; i < 8; ++i) {
        f16x8 o;
        #pragma unroll
        for (int c = 0; c < 8; ++c) {
            float a = bias[c];
            #pragma unroll
            for (int j = 0; j < 4; ++j)
                a = fmaf((float)r[i + j][c], w[c][j], a);
            o[c] = (f16)silu_f(a);
        }
        *(f16x8*)(uh + (size_t)(ml0 + i) * DINNER + d) = o;
    }
}

// ---------------------------------------------------------------------------
// Scan passes 2 & 3 (pass1 fused into delta_scan1).
// ---------------------------------------------------------------------------
__device__ __forceinline__ bool load_A(const float* __restrict__ A_log, int d,
                                       float* Av)
{
    #pragma unroll
    for (int n = 0; n < DSTATE; ++n)
        Av[n] = -__expf(A_log[(size_t)d * DSTATE + n]);
    bool p = true;
    #pragma unroll
    for (int n = 1; n < DSTATE; ++n) {
        const float r = Av[n] / Av[0];
        if (fabsf(r - (float)(n + 1)) > 1e-3f) p = false;
    }
    return p;
}

// pass2: thread per (b, d, n) -- serial over chunks only.
__global__ __launch_bounds__(256)
void scan_pass2(const float* __restrict__ A_log,
                const float* __restrict__ sumdt,
                f16* __restrict__ Sbufh)
{
    const int d = blockIdx.x * 64 + (threadIdx.x & 63);
    const int n = blockIdx.y * 4 + (threadIdx.x >> 6);
    const int b = blockIdx.z;

    const float Avn = -__expf(A_log[(size_t)d * DSTATE + n]);

    float h = 0.f;
    for (int c = 0; c < NCH; ++c) {
        const size_t base = (size_t)b * NCH + c;
        const float sdt = sumdt[base * DINNER + d];
        const size_t idx = (base * DSTATE + n) * DINNER + d;
        const float tmp = (float)Sbufh[idx];
        Sbufh[idx] = (f16)h;
        h = fmaf(h, __expf(sdt * Avn), tmp);
    }
}

__global__ __launch_bounds__(256)
void scan_pass3(const f16* __restrict__ uh,
                const f16* __restrict__ deltah,
                const f16* __restrict__ zh,
                const float* __restrict__ proj,
                const float* __restrict__ A_log,
                const float* __restrict__ Dp,
                const f16* __restrict__ Sbufh,
                f16* __restrict__ ygh)
{
    const int d = blockIdx.x * 256 + threadIdx.x;
    const int c = blockIdx.y;
    const int b = blockIdx.z;

    float Av[DSTATE];
    const bool pw = load_A(A_log, d, Av);
    const float Av0 = Av[0];

    float h[DSTATE];
    const size_t base = (size_t)b * NCH + c;
    #pragma unroll
    for (int n = 0; n < DSTATE; ++n)
        h[n] = (float)Sbufh[(base * DSTATE + n) * DINNER + d];

    const float Dval = Dp[d];
    const float* projb = proj + ((size_t)b * LSEQ + (size_t)c * CHUNK) * 96 + 64;

    const size_t tok0 = (size_t)b * LSEQ + (size_t)c * CHUNK;
    for (int l = 0; l < CHUNK; ++l) {
        const float* pr = projb + (size_t)l * 96;   // uniform: B at +0, C at +16
        const size_t tok = tok0 + l;
        const float dt = (float)deltah[tok * DINNER + d];
        const float uu = (float)uh[tok * DINNER + d];
        const float zz = (float)zh[tok * DINNER + d];
        const float du = dt * uu;
        float y = 0.f;
        if (pw) {
            const float p1 = __expf(dt * Av0);
            const float p2 = p1 * p1;
            const float p3 = p2 * p1;
            const float p4 = p2 * p2;
            float m = 1.f;
            #pragma unroll
            for (int g = 0; g < 4; ++g) {
                const f32x4 bb = *(const f32x4*)(pr + g * 4);
                const f32x4 cc = *(const f32x4*)(pr + 16 + g * 4);
                h[g*4+0] = fmaf(h[g*4+0], m * p1, du * bb[0]);
                h[g*4+1] = fmaf(h[g*4+1], m * p2, du * bb[1]);
                h[g*4+2] = fmaf(h[g*4+2], m * p3, du * bb[2]);
                h[g*4+3] = fmaf(h[g*4+3], m * p4, du * bb[3]);
                y = fmaf(h[g*4+0], cc[0], y);
                y = fmaf(h[g*4+1], cc[1], y);
                y = fmaf(h[g*4+2], cc[2], y);
                y = fmaf(h[g*4+3], cc[3], y);
                m *= p4;
            }
        } else {
            #pragma unroll
            for (int n = 0; n < DSTATE; ++n) {
                h[n] = fmaf(h[n], __expf(dt * Av[n]), du * pr[n]);
                y = fmaf(h[n], pr[16 + n], y);
            }
        }
        const float yt = fmaf(uu, Dval, y);
        ygh[tok * DINNER + d] = (f16)(yt * silu_f(zz));
    }
}

// ---------------------------------------------------------------------------
extern "C" void kernel_launch(void* const* d_in, const int* in_sizes, int n_in,
                              void* d_out, int out_size, void* d_ws, size_t ws_size,
                              hipStream_t stream)
{
    const float* x     = (const float*)d_in[0];
    const float* W_in  = (const float*)d_in[1];
    const float* cw    = (const float*)d_in[2];
    const float* cb    = (const float*)d_in[3];
    const float* W_xp  = (const float*)d_in[4];
    const float* W_dt  = (const float*)d_in[5];
    const float* b_dt  = (const float*)d_in[6];
    const float* A_log = (const float*)d_in[7];
    const float* Dp    = (const float*)d_in[8];
    const float* W_out = (const float*)d_in[9];
    float* out = (float*)d_out;

    // ---- workspace layout ----
    float* updelta = (float*)d_ws;                   // [MTOK][DINNER] f32 region: uph(f16) -> deltah(f16)
    f16*   zh      = (f16*)(updelta + (size_t)MTOK * DINNER);   // [MTOK][DINNER] f16
    f16*   uh      = zh + (size_t)MTOK * DINNER;     // [MTOK][DINNER] f16 (xh alias at base)
    float* proj    = (float*)(uh + (size_t)MTOK * DINNER);      // [MTOK][96] f32
    f16*   projh   = (f16*)(proj + NPROJ);           // [MTOK][96] f16
    f16*   Sbufh   = (f16*)(projh + NPROJ);          // [B][NCH][16][DINNER] f16
    float* sumdt   = (float*)(Sbufh + (size_t)NBATCH * NCH * DSTATE * DINNER * 2);
    f16*   WxpT    = (f16*)(sumdt + (size_t)NBATCH * NCH * DINNER);  // [96][DINNER]
    f16*   WdtT    = WxpT + (size_t)96 * DINNER;     // [DINNER][64]
    f16*   WoutT   = WdtT + (size_t)DINNER * DTRANK; // [DMODEL][DINNER]
    f16*   big     = WoutT + (size_t)DMODEL * DINNER;// 16.78M f16 alias region
    f16*   WinT    = big;                            // [NXZ][DMODEL] (phase 1)
    float* part3   = (float*)(big + (size_t)NXZ * DMODEL);  // [SPLITK][MTOK][96] (phase 2)
    f16*   ygh     = big;                            // [MTOK][DINNER] (phase 3)
    f16*   xh      = uh;                             // [MTOK][DMODEL] (pre-conv alias)
    f16*   uph     = (f16*)updelta;                  // [MTOK][DINNER] f16 (dead before delta)
    f16*   deltah  = (f16*)updelta;                  // [MTOK][DINNER] f16 (over uph)

    // 1) convert x, transpose-convert W_in; batch-convert small weights
    cvt_f2h<<<(MTOK * DMODEL / 4 + 255) / 256, 256, 0, stream>>>(x, xh, MTOK * DMODEL / 4);
    tcvt<<<dim3(NXZ / 32, DMODEL / 32), 256, 0, stream>>>(W_in, WinT, DMODEL, NXZ);
    tcvt3<<<2368, 256, 0, stream>>>(W_xp, WxpT, W_dt, WdtT, W_out, WoutT);

    // 2) GEMM1: [u_pre | z] = x @ W_in, 256x256 8-phase pipelined, split outputs
    hgemm256p<<<dim3(32, 16), 512, 0, stream>>>(
        xh, DMODEL, WinT, DMODEL, uph, DINNER, DMODEL, zh, DINNER);

    // 3) conv + silu -> uh f16   (clobbers xh)
    conv_silu_kernel<<<MTOK / 8, 256, 0, stream>>>(uph, cw, cb, uh);

    // 4) proj = u @ W_xproj  (split-K=4, N=96) + reduce
    hgemm_n96<<<dim3(64, SPLITK), 256, 0, stream>>>(uh, WxpT, part3);
    reduce3<<<NPROJ / 256, 256, 0, stream>>>(part3, proj, projh);

    // 5) FUSED: deltah = softplus(projh @ WdtT^T + b_dt)  +  scan pass1
    delta_scan1<<<dim3(64, 16), 256, 0, stream>>>(
        projh, WdtT, deltah, b_dt, uh, proj, A_log, Sbufh, sumdt);

    // 6) scan pass2 + pass3 -> ygh f16 (clobbers WinT/part3)
    scan_pass2<<<dim3(DINNER / 64, DSTATE / 4, NBATCH), 256, 0, stream>>>(
        A_log, sumdt, Sbufh);
    scan_pass3<<<dim3(DINNER / 256, NCH, NBATCH), 256, 0, stream>>>(
        uh, deltah, zh, proj, A_log, Dp, Sbufh, ygh);

    // 7) out = yg @ W_out
    hgemm128<0, float><<<dim3(64, 8), 256, 0, stream>>>(
        ygh, DINNER, WoutT, DINNER, out, DMODEL, DINNER, nullptr, nullptr, 0);
}

// Round 19
// 292.045 us; speedup vs baseline: 1.0726x; 1.0726x over previous
//
#include <hip/hip_runtime.h>
#include <hip/hip_bf16.h>
#include <math.h>

// Problem constants
#define MTOK   8192   // B*L
#define LSEQ   2048
#define NBATCH 4
#define DMODEL 1024
#define DINNER 2048
#define DSTATE 16
#define DTRANK 64
#define NXZ    4096
#define CHUNK  64
#define NCH    32     // LSEQ / CHUNK
#define NPROJ  (MTOK * 96)
#define SPLITK 4

typedef _Float16 f16;
using f16x8 = __attribute__((ext_vector_type(8))) _Float16;
using f16x4 = __attribute__((ext_vector_type(4))) _Float16;
using f32x4 = __attribute__((ext_vector_type(4))) float;

__device__ __forceinline__ float silu_f(float x) { return x / (1.f + __expf(-x)); }

// async global->LDS, 16B per lane; lds dest = wave-uniform base + lane*16B
__device__ __forceinline__ void gload_lds16(const void* g, void* l) {
    __builtin_amdgcn_global_load_lds(
        (const __attribute__((address_space(1))) void*)g,
        (__attribute__((address_space(3))) void*)l, 16, 0, 0);
}

// ---------------------------------------------------------------------------
// f32 -> f16 elementwise (vec4)
// ---------------------------------------------------------------------------
__global__ __launch_bounds__(256)
void cvt_f2h(const float* __restrict__ in, f16* __restrict__ out, int n4)
{
    const int i = blockIdx.x * 256 + threadIdx.x;
    if (i >= n4) return;
    const float4 v = ((const float4*)in)[i];
    f16x4 o;
    o[0] = (f16)v.x; o[1] = (f16)v.y; o[2] = (f16)v.z; o[3] = (f16)v.w;
    ((f16x4*)out)[i] = o;
}

// ---------------------------------------------------------------------------
// Transpose + convert body: in f32 [R][C] -> out f16 [C][R], 32x32 tile.
// ---------------------------------------------------------------------------
__device__ __forceinline__ void tcvt_body(const float* __restrict__ in,
                                          f16* __restrict__ out,
                                          int R, int C, int bx, int by)
{
    __shared__ float t[32][33];
    const int c0 = bx * 32, r0 = by * 32;
    const int tx = threadIdx.x & 31, ty = threadIdx.x >> 5;   // 32 x 8
    #pragma unroll
    for (int j = 0; j < 4; ++j)
        t[ty + 8 * j][tx] = in[(size_t)(r0 + ty + 8 * j) * C + c0 + tx];
    __syncthreads();
    #pragma unroll
    for (int j = 0; j < 4; ++j)
        out[(size_t)(c0 + ty + 8 * j) * R + r0 + tx] = (f16)t[tx][ty + 8 * j];
}

__global__ __launch_bounds__(256)
void tcvt(const float* __restrict__ in, f16* __restrict__ out, int R, int C)
{
    tcvt_body(in, out, R, C, blockIdx.x, blockIdx.y);
}

// Batched transpose of the three small weights in one dispatch.
__global__ __launch_bounds__(256)
void tcvt3(const float* __restrict__ W_xp, f16* __restrict__ WxpT,
           const float* __restrict__ W_dt, f16* __restrict__ WdtT,
           const float* __restrict__ W_out, f16* __restrict__ WoutT)
{
    int id = blockIdx.x;
    if (id < 192) {
        tcvt_body(W_xp, WxpT, DINNER, 96, id % 3, id / 3);
    } else if (id < 320) {
        id -= 192;
        tcvt_body(W_dt, WdtT, DTRANK, DINNER, id % 64, id / 64);
    } else {
        id -= 320;
        tcvt_body(W_out, WoutT, DINNER, DMODEL, id % 32, id / 32);
    }
}

// ---------------------------------------------------------------------------
// 256x256 8-phase deep-pipelined FP16 GEMM (m201 template, T2+T3+T4+T5).
// 3-bit G4 swizzle, counted vmcnt, conflict-free.
// ---------------------------------------------------------------------------
__global__ __launch_bounds__(512, 1)
void hgemm256p(const f16* __restrict__ A, int lda,
               const f16* __restrict__ Bt, int ldb,
               f16* __restrict__ C, int ldc,
               int K, f16* __restrict__ C2, int splitcol)
{
    __shared__ __align__(16) f16 SA[2][16384];
    __shared__ __align__(16) f16 SB[2][16384];

    const int tid  = threadIdx.x;
    const int lane = tid & 63, w = tid >> 6;
    const int wr = w >> 2, wc = w & 3;            // 2 x 4 wave grid
    const int row0 = blockIdx.x * 256;
    int col0 = blockIdx.y * 256;

    const int frow = lane & 15;
    const int nt = K / 64;

    auto issue_half = [&](int q) {
        const int t = q >> 2, j = q & 3, buf = t & 1, k0 = t * 64;
        const bool isA = (j >= 2);
        const int hh = j & 1;
        const f16* base = isA ? (A  + (size_t)(row0 + hh * 128) * lda + k0)
                              : (Bt + (size_t)(col0 + hh * 128) * ldb + k0);
        const int ld = isA ? lda : ldb;
        f16* dst = (isA ? &SA[buf][0] : &SB[buf][0]) + hh * 8192;
        #pragma unroll
        for (int r2 = 0; r2 < 2; ++r2) {
            const int ch = r2 * 512 + tid;        // 16B unit index
            const int grow  = ch >> 3;            // row 0..127
            const int gunit = (ch & 7) ^ (grow & 7);   // inverse swizzle
            gload_lds16(base + (size_t)grow * ld + gunit * 8, dst + ch * 8);
        }
    };

    int next = 0;
    for (; next < 6 && next < 4 * nt; ++next) issue_half(next);
    asm volatile("s_waitcnt vmcnt(4)" ::: "memory");
    asm volatile("s_barrier" ::: "memory");

    f32x4 acc[8][4] = {};

    for (int t = 0; t < nt; ++t) {
        const int buf = t & 1;
        const char* Ab = (const char*)&SA[buf][0];
        const char* Bb = (const char*)&SB[buf][0];
        f16x8 bf[4][2];
        #pragma unroll
        for (int p = 0; p < 4; ++p) {
            f16x8 af[2][2];
            if (p == 0) {
                #pragma unroll
                for (int n = 0; n < 4; ++n)
                    #pragma unroll
                    for (int ks = 0; ks < 2; ++ks) {
                        const int R = wc * 64 + n * 16 + frow;
                        const int off = R * 128 +
                            ((ks * 64 + (lane >> 4) * 16) ^ ((R & 7) << 4));
                        bf[n][ks] = *(const f16x8*)(Bb + off);
                    }
            }
            #pragma unroll
            for (int i = 0; i < 2; ++i)
                #pragma unroll
                for (int ks = 0; ks < 2; ++ks) {
                    const int R = wr * 128 + (2 * p + i) * 16 + frow;
                    const int off = R * 128 +
                        ((ks * 64 + (lane >> 4) * 16) ^ ((R & 7) << 4));
                    af[i][ks] = *(const f16x8*)(Ab + off);
                }
            if (next < 4 * nt) issue_half(next++);
            asm volatile("s_barrier" ::: "memory");
            asm volatile("s_waitcnt lgkmcnt(0)" ::: "memory");
            __builtin_amdgcn_sched_barrier(0);
            __builtin_amdgcn_s_setprio(1);
            #pragma unroll
            for (int i = 0; i < 2; ++i)
                #pragma unroll
                for (int n = 0; n < 4; ++n)
                    #pragma unroll
                    for (int ks = 0; ks < 2; ++ks)
                        acc[2 * p + i][n] = __builtin_amdgcn_mfma_f32_16x16x32_f16(
                            af[i][ks], bf[n][ks], acc[2 * p + i][n], 0, 0, 0);
            __builtin_amdgcn_s_setprio(0);
            if (p == 3 && t + 1 < nt) {
                if (next >= 4 * t + 10) asm volatile("s_waitcnt vmcnt(4)" ::: "memory");
                else                    asm volatile("s_waitcnt vmcnt(0)" ::: "memory");
            }
            asm volatile("s_barrier" ::: "memory");
        }
    }

    f16* Cw = C;
    if (C2 != nullptr && col0 >= splitcol) { Cw = C2; col0 -= splitcol; }

    const int rbase = row0 + wr * 128 + (lane >> 4) * 4;
    const int cbase = col0 + wc * 64 + (lane & 15);
    #pragma unroll
    for (int m = 0; m < 8; ++m) {
        #pragma unroll
        for (int n = 0; n < 4; ++n) {
            const int col = cbase + n * 16;
            #pragma unroll
            for (int r = 0; r < 4; ++r)
                Cw[(size_t)(rbase + m * 16 + r) * ldc + col] = (f16)acc[m][n][r];
        }
    }
}

// ---------------------------------------------------------------------------
// FP16 MFMA GEMM, m97 double-buffer + XOR unit-swizzle (T2, both sides).
// Used for delta and out GEMMs.
// ---------------------------------------------------------------------------
template<int EPI, typename OUT_T>
__global__ __launch_bounds__(256)
void hgemm128(const f16* __restrict__ A, int lda,
              const f16* __restrict__ Bt, int ldb,
              OUT_T* __restrict__ C, int ldc,
              int K, const float* __restrict__ bias,
              OUT_T* __restrict__ C2, int splitcol)
{
    __shared__ __align__(16) f16 As[2][128 * 32];
    __shared__ __align__(16) f16 Bs[2][128 * 32];

    const int tid  = threadIdx.x;
    const int lane = tid & 63, wave = tid >> 6;
    const int wr = wave >> 1, wc = wave & 1;
    const int row0 = blockIdx.x * 128;
    int col0 = blockIdx.y * 128;

    const int lrow = lane >> 2;
    const int lcol = ((lane & 3) ^ ((lane >> 3) & 3)) * 8;
    const f16* Agw = A  + (size_t)(row0 + wave * 32 + lrow) * lda + lcol;
    const f16* Bgw = Bt + (size_t)(col0 + wave * 32 + lrow) * ldb + lcol;
    const int ldsbase = (wave * 32) * 32;   // elems

    const int frow = lane & 15;
    const int fk   = (((lane >> 4) ^ ((frow >> 1) & 3))) * 8;
    const int nt = K / 32;

    f32x4 acc[4][4] = {};

    #pragma unroll
    for (int r = 0; r < 2; ++r) {
        gload_lds16(Agw + (size_t)r * 16 * lda, &As[0][ldsbase + r * 16 * 32]);
        gload_lds16(Bgw + (size_t)r * 16 * ldb, &Bs[0][ldsbase + r * 16 * 32]);
    }

    int cur = 0;
    for (int kt = 0; kt < nt; ++kt) {
        __syncthreads();
        if (kt + 1 < nt) {
            const int k0 = (kt + 1) * 32;
            #pragma unroll
            for (int r = 0; r < 2; ++r) {
                gload_lds16(Agw + (size_t)r * 16 * lda + k0, &As[cur ^ 1][ldsbase + r * 16 * 32]);
                gload_lds16(Bgw + (size_t)r * 16 * ldb + k0, &Bs[cur ^ 1][ldsbase + r * 16 * 32]);
            }
        }
        f16x8 af[4], bf[4];
        #pragma unroll
        for (int m = 0; m < 4; ++m)
            af[m] = *(const f16x8*)&As[cur][(wr * 64 + m * 16 + frow) * 32 + fk];
        #pragma unroll
        for (int n = 0; n < 4; ++n)
            bf[n] = *(const f16x8*)&Bs[cur][(wc * 64 + n * 16 + frow) * 32 + fk];
        #pragma unroll
        for (int m = 0; m < 4; ++m)
            #pragma unroll
            for (int n = 0; n < 4; ++n)
                acc[m][n] = __builtin_amdgcn_mfma_f32_16x16x32_f16(af[m], bf[n], acc[m][n], 0, 0, 0);
        cur ^= 1;
    }

    OUT_T* Cw = C;
    if (C2 != nullptr && col0 >= splitcol) { Cw = C2; col0 -= splitcol; }

    const int rbase = row0 + wr * 64 + (lane >> 4) * 4;
    const int cbase = col0 + wc * 64 + (lane & 15);
    #pragma unroll
    for (int m = 0; m < 4; ++m) {
        #pragma unroll
        for (int n = 0; n < 4; ++n) {
            const int col = cbase + n * 16;
            #pragma unroll
            for (int r = 0; r < 4; ++r) {
                const int row = rbase + m * 16 + r;
                float tv = acc[m][n][r];
                if (EPI == 1) {
                    tv += bias[col];
                    tv = (tv > 20.f) ? tv : __logf(1.f + __expf(tv));
                }
                Cw[(size_t)row * ldc + col] = (OUT_T)tv;
            }
        }
    }
}

// ---------------------------------------------------------------------------
// Narrow-N GEMM for proj: part[sk] = uh[rows][kseg] @ WxpT^T, N=96, split-K=4.
// ---------------------------------------------------------------------------
__global__ __launch_bounds__(256)
void hgemm_n96(const f16* __restrict__ A,      // uh [MTOK][DINNER]
               const f16* __restrict__ Bt,     // WxpT [96][DINNER]
               float* __restrict__ part)       // [SPLITK][MTOK][96]
{
    __shared__ __align__(16) f16 As[128][40];
    __shared__ __align__(16) f16 Bs[96][40];

    const int tid = threadIdx.x, lane = tid & 63, wave = tid >> 6;
    const int row0 = blockIdx.x * 128;
    const int sk = blockIdx.y;
    const int kbase = sk * (DINNER / SPLITK);   // 512

    const int srow = tid >> 1, skoff = (tid & 1) * 16;
    const f16* Ag = A  + (size_t)(row0 + srow) * DINNER + kbase + skoff;
    const f16* Bg = Bt + (size_t)srow * DINNER + kbase + skoff;

    const int frow = lane & 15, fk = (lane >> 4) * 8;

    f32x4 acc[2][6] = {};

    for (int kk = 0; kk < DINNER / SPLITK; kk += 32) {
        const f16x8 a0 = *(const f16x8*)(Ag + kk);
        const f16x8 a1 = *(const f16x8*)(Ag + kk + 8);
        f16x8 b0 = {}, b1 = {};
        if (tid < 192) { b0 = *(const f16x8*)(Bg + kk); b1 = *(const f16x8*)(Bg + kk + 8); }
        __syncthreads();
        *(f16x8*)&As[srow][skoff]     = a0;
        *(f16x8*)&As[srow][skoff + 8] = a1;
        if (tid < 192) {
            *(f16x8*)&Bs[srow][skoff]     = b0;
            *(f16x8*)&Bs[srow][skoff + 8] = b1;
        }
        __syncthreads();

        f16x8 af[2], bf[6];
        #pragma unroll
        for (int m = 0; m < 2; ++m)
            af[m] = *(const f16x8*)&As[wave * 32 + m * 16 + frow][fk];
        #pragma unroll
        for (int n = 0; n < 6; ++n)
            bf[n] = *(const f16x8*)&Bs[n * 16 + frow][fk];
        #pragma unroll
        for (int m = 0; m < 2; ++m)
            #pragma unroll
            for (int n = 0; n < 6; ++n)
                acc[m][n] = __builtin_amdgcn_mfma_f32_16x16x32_f16(af[m], bf[n], acc[m][n], 0, 0, 0);
    }

    #pragma unroll
    for (int m = 0; m < 2; ++m)
        #pragma unroll
        for (int n = 0; n < 6; ++n) {
            const int col = n * 16 + (lane & 15);
            #pragma unroll
            for (int r = 0; r < 4; ++r) {
                const int row = row0 + wave * 32 + m * 16 + (lane >> 4) * 4 + r;
                part[((size_t)sk * MTOK + row) * 96 + col] = acc[m][n][r];
            }
        }
}

__global__ __launch_bounds__(256)
void reduce3(const float* __restrict__ part, float* __restrict__ proj,
             f16* __restrict__ projh)
{
    const int e = blockIdx.x * 256 + threadIdx.x;   // < NPROJ
    float s = 0.f;
    #pragma unroll
    for (int i = 0; i < SPLITK; ++i) s += part[(size_t)i * NPROJ + e];
    proj[e]  = s;
    projh[e] = (f16)s;
}

// ---------------------------------------------------------------------------
// Causal depthwise conv (D_CONV=4) + bias + SiLU, sliding-window.
// ---------------------------------------------------------------------------
__global__ __launch_bounds__(256)
void conv_silu_kernel(const f16* __restrict__ uph,
                      const float* __restrict__ cw, const float* __restrict__ cb,
                      f16* __restrict__ uh)
{
    const int mt  = blockIdx.x;          // 0 .. MTOK/8-1
    const int ml0 = mt * 8;
    const int l0  = ml0 & (LSEQ - 1);
    const int d   = threadIdx.x * 8;

    float w[8][4];
    #pragma unroll
    for (int c = 0; c < 8; ++c) {
        const float4 wv = *(const float4*)(cw + (size_t)(d + c) * 4);
        w[c][0] = wv.x; w[c][1] = wv.y; w[c][2] = wv.z; w[c][3] = wv.w;
    }
    float bias[8];
    {
        const float4 b0 = *(const float4*)(cb + d);
        const float4 b1 = *(const float4*)(cb + d + 4);
        bias[0] = b0.x; bias[1] = b0.y; bias[2] = b0.z; bias[3] = b0.w;
        bias[4] = b1.x; bias[5] = b1.y; bias[6] = b1.z; bias[7] = b1.w;
    }

    f16x8 r[11];
    if (l0 != 0) {
        #pragma unroll
        for (int i = 0; i < 11; ++i)
            r[i] = *(const f16x8*)(uph + (size_t)(ml0 - 3 + i) * DINNER + d);
    } else {
        r[0] = f16x8{}; r[1] = f16x8{}; r[2] = f16x8{};
        #pragma unroll
        for (int i = 3; i < 11; ++i)
            r[i] = *(const f16x8*)(uph + (size_t)(ml0 - 3 + i) * DINNER + d);
    }

    #pragma unroll
    for (int i = 0; i < 8; ++i) {
        f16x8 o;
        #pragma unroll
        for (int c = 0; c < 8; ++c) {
            float a = bias[c];
            #pragma unroll
            for (int j = 0; j < 4; ++j)
                a = fmaf((float)r[i + j][c], w[c][j], a);
            o[c] = (f16)silu_f(a);
        }
        *(f16x8*)(uh + (size_t)(ml0 + i) * DINNER + d) = o;
    }
}

// ---------------------------------------------------------------------------
// Chunked selective scan.  A-structure fast path (A[d][n] = (n+1)*A[d][0],
// true here: A = -[1..16]): exp(dt*A[n]) = e1^(n+1), power ladder depth ~4.
// B/C rows block-uniform -> scalar-pipe global loads; Sbuf stored f16.
// ---------------------------------------------------------------------------
__device__ __forceinline__ bool load_A(const float* __restrict__ A_log, int d,
                                       float* Av)
{
    #pragma unroll
    for (int n = 0; n < DSTATE; ++n)
        Av[n] = -__expf(A_log[(size_t)d * DSTATE + n]);
    bool p = true;
    #pragma unroll
    for (int n = 1; n < DSTATE; ++n) {
        const float r = Av[n] / Av[0];
        if (fabsf(r - (float)(n + 1)) > 1e-3f) p = false;
    }
    return p;
}

__global__ __launch_bounds__(256)
void scan_pass1(const f16* __restrict__ uh,
                const f16* __restrict__ deltah,    // [MTOK][DINNER] f16
                const float* __restrict__ proj,    // [MTOK][96], 64..95 = B,C
                const float* __restrict__ A_log,
                f16* __restrict__ Sbufh, float* __restrict__ sumdt)
{
    const int d = blockIdx.x * 256 + threadIdx.x;
    const int c = blockIdx.y;
    const int b = blockIdx.z;

    float Av[DSTATE];
    const bool pw = load_A(A_log, d, Av);
    const float Av0 = Av[0];

    const float* projb = proj + ((size_t)b * LSEQ + (size_t)c * CHUNK) * 96 + 64;

    float S[DSTATE];
    #pragma unroll
    for (int n = 0; n < DSTATE; ++n) S[n] = 0.f;
    float sdt = 0.f;

    const size_t tok0 = (size_t)b * LSEQ + (size_t)c * CHUNK;
    if (pw) {
        for (int l = 0; l < CHUNK; ++l) {
            const float* pr = projb + (size_t)l * 96;   // uniform address
            const float dt = (float)deltah[(tok0 + l) * DINNER + d];
            const float uu = (float)uh[(tok0 + l) * DINNER + d];
            sdt += dt;
            const float du = dt * uu;
            const float p1 = __expf(dt * Av0);
            const float p2 = p1 * p1;
            const float p3 = p2 * p1;
            const float p4 = p2 * p2;
            float m = 1.f;
            #pragma unroll
            for (int g = 0; g < 4; ++g) {
                const f32x4 bb = *(const f32x4*)(pr + g * 4);
                S[g*4+0] = fmaf(S[g*4+0], m * p1, du * bb[0]);
                S[g*4+1] = fmaf(S[g*4+1], m * p2, du * bb[1]);
                S[g*4+2] = fmaf(S[g*4+2], m * p3, du * bb[2]);
                S[g*4+3] = fmaf(S[g*4+3], m * p4, du * bb[3]);
                m *= p4;
            }
        }
    } else {
        for (int l = 0; l < CHUNK; ++l) {
            const float* pr = projb + (size_t)l * 96;
            const float dt = (float)deltah[(tok0 + l) * DINNER + d];
            const float uu = (float)uh[(tok0 + l) * DINNER + d];
            sdt += dt;
            const float du = dt * uu;
            #pragma unroll
            for (int n = 0; n < DSTATE; ++n)
                S[n] = fmaf(S[n], __expf(dt * Av[n]), du * pr[n]);
        }
    }

    const size_t base = (size_t)b * NCH + c;
    #pragma unroll
    for (int n = 0; n < DSTATE; ++n)
        Sbufh[(base * DSTATE + n) * DINNER + d] = (f16)S[n];
    sumdt[base * DINNER + d] = sdt;
}

// pass2: thread per (b, d, n) -- serial over chunks only.
__global__ __launch_bounds__(256)
void scan_pass2(const float* __restrict__ A_log,
                const float* __restrict__ sumdt,
                f16* __restrict__ Sbufh)
{
    const int d = blockIdx.x * 64 + (threadIdx.x & 63);
    const int n = blockIdx.y * 4 + (threadIdx.x >> 6);
    const int b = blockIdx.z;

    const float Avn = -__expf(A_log[(size_t)d * DSTATE + n]);

    float h = 0.f;
    for (int c = 0; c < NCH; ++c) {
        const size_t base = (size_t)b * NCH + c;
        const float sdt = sumdt[base * DINNER + d];
        const size_t idx = (base * DSTATE + n) * DINNER + d;
        const float tmp = (float)Sbufh[idx];
        Sbufh[idx] = (f16)h;
        h = fmaf(h, __expf(sdt * Avn), tmp);
    }
}

__global__ __launch_bounds__(256)
void scan_pass3(const f16* __restrict__ uh,
                const f16* __restrict__ deltah,
                const f16* __restrict__ zh,
                const float* __restrict__ proj,
                const float* __restrict__ A_log,
                const float* __restrict__ Dp,
                const f16* __restrict__ Sbufh,
                f16* __restrict__ ygh)
{
    const int d = blockIdx.x * 256 + threadIdx.x;
    const int c = blockIdx.y;
    const int b = blockIdx.z;

    float Av[DSTATE];
    const bool pw = load_A(A_log, d, Av);
    const float Av0 = Av[0];

    float h[DSTATE];
    const size_t base = (size_t)b * NCH + c;
    #pragma unroll
    for (int n = 0; n < DSTATE; ++n)
        h[n] = (float)Sbufh[(base * DSTATE + n) * DINNER + d];

    const float Dval = Dp[d];
    const float* projb = proj + ((size_t)b * LSEQ + (size_t)c * CHUNK) * 96 + 64;

    const size_t tok0 = (size_t)b * LSEQ + (size_t)c * CHUNK;
    for (int l = 0; l < CHUNK; ++l) {
        const float* pr = projb + (size_t)l * 96;   // uniform: B at +0, C at +16
        const size_t tok = tok0 + l;
        const float dt = (float)deltah[tok * DINNER + d];
        const float uu = (float)uh[tok * DINNER + d];
        const float zz = (float)zh[tok * DINNER + d];
        const float du = dt * uu;
        float y = 0.f;
        if (pw) {
            const float p1 = __expf(dt * Av0);
            const float p2 = p1 * p1;
            const float p3 = p2 * p1;
            const float p4 = p2 * p2;
            float m = 1.f;
            #pragma unroll
            for (int g = 0; g < 4; ++g) {
                const f32x4 bb = *(const f32x4*)(pr + g * 4);
                const f32x4 cc = *(const f32x4*)(pr + 16 + g * 4);
                h[g*4+0] = fmaf(h[g*4+0], m * p1, du * bb[0]);
                h[g*4+1] = fmaf(h[g*4+1], m * p2, du * bb[1]);
                h[g*4+2] = fmaf(h[g*4+2], m * p3, du * bb[2]);
                h[g*4+3] = fmaf(h[g*4+3], m * p4, du * bb[3]);
                y = fmaf(h[g*4+0], cc[0], y);
                y = fmaf(h[g*4+1], cc[1], y);
                y = fmaf(h[g*4+2], cc[2], y);
                y = fmaf(h[g*4+3], cc[3], y);
                m *= p4;
            }
        } else {
            #pragma unroll
            for (int n = 0; n < DSTATE; ++n) {
                h[n] = fmaf(h[n], __expf(dt * Av[n]), du * pr[n]);
                y = fmaf(h[n], pr[16 + n], y);
            }
        }
        const float yt = fmaf(uu, Dval, y);
        ygh[tok * DINNER + d] = (f16)(yt * silu_f(zz));
    }
}

// ---------------------------------------------------------------------------
extern "C" void kernel_launch(void* const* d_in, const int* in_sizes, int n_in,
                              void* d_out, int out_size, void* d_ws, size_t ws_size,
                              hipStream_t stream)
{
    const float* x     = (const float*)d_in[0];
    const float* W_in  = (const float*)d_in[1];
    const float* cw    = (const float*)d_in[2];
    const float* cb    = (const float*)d_in[3];
    const float* W_xp  = (const float*)d_in[4];
    const float* W_dt  = (const float*)d_in[5];
    const float* b_dt  = (const float*)d_in[6];
    const float* A_log = (const float*)d_in[7];
    const float* Dp    = (const float*)d_in[8];
    const float* W_out = (const float*)d_in[9];
    float* out = (float*)d_out;

    // ---- workspace layout ----
    float* updelta = (float*)d_ws;                   // [MTOK][DINNER] f32 region: uph(f16) -> deltah(f16)
    f16*   zh      = (f16*)(updelta + (size_t)MTOK * DINNER);   // [MTOK][DINNER] f16
    f16*   uh      = zh + (size_t)MTOK * DINNER;     // [MTOK][DINNER] f16 (xh alias at base)
    float* proj    = (float*)(uh + (size_t)MTOK * DINNER);      // [MTOK][96] f32
    f16*   projh   = (f16*)(proj + NPROJ);           // [MTOK][96] f16
    f16*   Sbufh   = (f16*)(projh + NPROJ);          // [B][NCH][16][DINNER] f16
    float* sumdt   = (float*)(Sbufh + (size_t)NBATCH * NCH * DSTATE * DINNER * 2);
    f16*   WxpT    = (f16*)(sumdt + (size_t)NBATCH * NCH * DINNER);  // [96][DINNER]
    f16*   WdtT    = WxpT + (size_t)96 * DINNER;     // [DINNER][64]
    f16*   WoutT   = WdtT + (size_t)DINNER * DTRANK; // [DMODEL][DINNER]
    f16*   big     = WoutT + (size_t)DMODEL * DINNER;// 16.78M f16 alias region
    f16*   WinT    = big;                            // [NXZ][DMODEL] (phase 1)
    float* part3   = (float*)(big + (size_t)NXZ * DMODEL);  // [SPLITK][MTOK][96] (phase 2)
    f16*   ygh     = big;                            // [MTOK][DINNER] (phase 3)
    f16*   xh      = uh;                             // [MTOK][DMODEL] (pre-conv alias)
    f16*   uph     = (f16*)updelta;                  // [MTOK][DINNER] f16 (dead before delta)
    f16*   deltah  = (f16*)updelta;                  // [MTOK][DINNER] f16 (over uph)

    // 1) convert x, transpose-convert W_in; batch-convert small weights
    cvt_f2h<<<(MTOK * DMODEL / 4 + 255) / 256, 256, 0, stream>>>(x, xh, MTOK * DMODEL / 4);
    tcvt<<<dim3(NXZ / 32, DMODEL / 32), 256, 0, stream>>>(W_in, WinT, DMODEL, NXZ);
    tcvt3<<<2368, 256, 0, stream>>>(W_xp, WxpT, W_dt, WdtT, W_out, WoutT);

    // 2) GEMM1: [u_pre | z] = x @ W_in, 256x256 8-phase pipelined, split outputs
    hgemm256p<<<dim3(32, 16), 512, 0, stream>>>(
        xh, DMODEL, WinT, DMODEL, uph, DINNER, DMODEL, zh, DINNER);

    // 3) conv + silu -> uh f16   (clobbers xh)
    conv_silu_kernel<<<MTOK / 8, 256, 0, stream>>>(uph, cw, cb, uh);

    // 4) proj = u @ W_xproj  (split-K=4, N=96) + reduce
    hgemm_n96<<<dim3(64, SPLITK), 256, 0, stream>>>(uh, WxpT, part3);
    reduce3<<<NPROJ / 256, 256, 0, stream>>>(part3, proj, projh);

    // 5) deltah = softplus(proj[:, :64] @ W_dt + b_dt) f16 (uph dead)
    hgemm128<1, f16><<<dim3(64, 16), 256, 0, stream>>>(
        projh, 96, WdtT, DTRANK, deltah, DINNER, DTRANK, b_dt, nullptr, 0);

    // 6) chunked scan + skip + gate -> ygh f16 (clobbers WinT/part3)
    scan_pass1<<<dim3(DINNER / 256, NCH, NBATCH), 256, 0, stream>>>(
        uh, deltah, proj, A_log, Sbufh, sumdt);
    scan_pass2<<<dim3(DINNER / 64, DSTATE / 4, NBATCH), 256, 0, stream>>>(
        A_log, sumdt, Sbufh);
    scan_pass3<<<dim3(DINNER / 256, NCH, NBATCH), 256, 0, stream>>>(
        uh, deltah, zh, proj, A_log, Dp, Sbufh, ygh);

    // 7) out = yg @ W_out
    hgemm128<0, float><<<dim3(64, 8), 256, 0, stream>>>(
        ygh, DINNER, WoutT, DINNER, out, DMODEL, DINNER, nullptr, nullptr, 0);
}

// Round 20
// 286.980 us; speedup vs baseline: 1.0915x; 1.0176x over previous
//
#include <hip/hip_runtime.h>
#include <hip/hip_bf16.h>
#include <math.h>

// Problem constants
#define MTOK   8192   // B*L
#define LSEQ   2048
#define NBATCH 4
#define DMODEL 1024
#define DINNER 2048
#define DSTATE 16
#define DTRANK 64
#define NXZ    4096
#define CHUNK  64
#define NCH    32     // LSEQ / CHUNK
#define NPROJ  (MTOK * 96)
#define SPLITK 4

typedef _Float16 f16;
using f16x8 = __attribute__((ext_vector_type(8))) _Float16;
using f16x4 = __attribute__((ext_vector_type(4))) _Float16;
using f32x4 = __attribute__((ext_vector_type(4))) float;

__device__ __forceinline__ float silu_f(float x) { return x / (1.f + __expf(-x)); }

// async global->LDS, 16B per lane; lds dest = wave-uniform base + lane*16B
__device__ __forceinline__ void gload_lds16(const void* g, void* l) {
    __builtin_amdgcn_global_load_lds(
        (const __attribute__((address_space(1))) void*)g,
        (__attribute__((address_space(3))) void*)l, 16, 0, 0);
}

// ---------------------------------------------------------------------------
// Transpose + convert body: in f32 [R][C] -> out f16 [C][R], 32x32 tile.
// ---------------------------------------------------------------------------
__device__ __forceinline__ void tcvt_body(const float* __restrict__ in,
                                          f16* __restrict__ out,
                                          int R, int C, int bx, int by)
{
    __shared__ float t[32][33];
    const int c0 = bx * 32, r0 = by * 32;
    const int tx = threadIdx.x & 31, ty = threadIdx.x >> 5;   // 32 x 8
    #pragma unroll
    for (int j = 0; j < 4; ++j)
        t[ty + 8 * j][tx] = in[(size_t)(r0 + ty + 8 * j) * C + c0 + tx];
    __syncthreads();
    #pragma unroll
    for (int j = 0; j < 4; ++j)
        out[(size_t)(c0 + ty + 8 * j) * R + r0 + tx] = (f16)t[tx][ty + 8 * j];
}

// One dispatch for ALL input prep: x->f16, W_in/W_xp/W_dt/W_out transpose+cvt.
// blocks: [0,8192) cvt x | [ ,12288) W_in | [ ,12480) W_xp | [ ,12608) W_dt |
// [ ,14656) W_out.  Branch is block-uniform.
__global__ __launch_bounds__(256)
void prep_all(const float* __restrict__ x, f16* __restrict__ xh,
              const float* __restrict__ W_in, f16* __restrict__ WinT,
              const float* __restrict__ W_xp, f16* __restrict__ WxpT,
              const float* __restrict__ W_dt, f16* __restrict__ WdtT,
              const float* __restrict__ W_out, f16* __restrict__ WoutT)
{
    int id = blockIdx.x;
    if (id < 8192) {
        const int i = id * 256 + threadIdx.x;   // covers MTOK*DMODEL/4 exactly
        const float4 v = ((const float4*)x)[i];
        f16x4 o;
        o[0] = (f16)v.x; o[1] = (f16)v.y; o[2] = (f16)v.z; o[3] = (f16)v.w;
        ((f16x4*)xh)[i] = o;
        return;
    }
    id -= 8192;
    if (id < 4096) { tcvt_body(W_in, WinT, DMODEL, NXZ, id % 128, id / 128); return; }
    id -= 4096;
    if (id < 192)  { tcvt_body(W_xp, WxpT, DINNER, 96, id % 3, id / 3); return; }
    id -= 192;
    if (id < 128)  { tcvt_body(W_dt, WdtT, DTRANK, DINNER, id % 64, id / 64); return; }
    id -= 128;
    tcvt_body(W_out, WoutT, DINNER, DMODEL, id % 32, id / 32);
}

// ---------------------------------------------------------------------------
// 256x256 deep-pipelined FP16 GEMM (T2+T3+T4+T5), 2 phases per K-tile:
// 32 MFMA per barrier-pair (halves sync overhead vs the 4-phase variant;
// identical data movement, swizzle, and vmcnt counting).
// ---------------------------------------------------------------------------
__global__ __launch_bounds__(512, 1)
void hgemm256p(const f16* __restrict__ A, int lda,
               const f16* __restrict__ Bt, int ldb,
               f16* __restrict__ C, int ldc,
               int K, f16* __restrict__ C2, int splitcol)
{
    __shared__ __align__(16) f16 SA[2][16384];
    __shared__ __align__(16) f16 SB[2][16384];

    const int tid  = threadIdx.x;
    const int lane = tid & 63, w = tid >> 6;
    const int wr = w >> 2, wc = w & 3;            // 2 x 4 wave grid
    const int row0 = blockIdx.x * 256;
    int col0 = blockIdx.y * 256;

    const int frow = lane & 15;
    const int nt = K / 64;

    auto issue_half = [&](int q) {
        const int t = q >> 2, j = q & 3, buf = t & 1, k0 = t * 64;
        const bool isA = (j >= 2);
        const int hh = j & 1;
        const f16* base = isA ? (A  + (size_t)(row0 + hh * 128) * lda + k0)
                              : (Bt + (size_t)(col0 + hh * 128) * ldb + k0);
        const int ld = isA ? lda : ldb;
        f16* dst = (isA ? &SA[buf][0] : &SB[buf][0]) + hh * 8192;
        #pragma unroll
        for (int r2 = 0; r2 < 2; ++r2) {
            const int ch = r2 * 512 + tid;        // 16B unit index
            const int grow  = ch >> 3;            // row 0..127
            const int gunit = (ch & 7) ^ (grow & 7);   // inverse swizzle
            gload_lds16(base + (size_t)grow * ld + gunit * 8, dst + ch * 8);
        }
    };

    int next = 0;
    for (; next < 6 && next < 4 * nt; ++next) issue_half(next);
    asm volatile("s_waitcnt vmcnt(4)" ::: "memory");
    asm volatile("s_barrier" ::: "memory");

    f32x4 acc[8][4] = {};

    for (int t = 0; t < nt; ++t) {
        const int buf = t & 1;
        const char* Ab = (const char*)&SA[buf][0];
        const char* Bb = (const char*)&SB[buf][0];
        f16x8 bf[4][2];
        #pragma unroll
        for (int p = 0; p < 2; ++p) {
            f16x8 af[4][2];
            if (p == 0) {
                #pragma unroll
                for (int n = 0; n < 4; ++n)
                    #pragma unroll
                    for (int ks = 0; ks < 2; ++ks) {
                        const int R = wc * 64 + n * 16 + frow;
                        const int off = R * 128 +
                            ((ks * 64 + (lane >> 4) * 16) ^ ((R & 7) << 4));
                        bf[n][ks] = *(const f16x8*)(Bb + off);
                    }
            }
            #pragma unroll
            for (int i = 0; i < 4; ++i)
                #pragma unroll
                for (int ks = 0; ks < 2; ++ks) {
                    const int R = wr * 128 + (4 * p + i) * 16 + frow;
                    const int off = R * 128 +
                        ((ks * 64 + (lane >> 4) * 16) ^ ((R & 7) << 4));
                    af[i][ks] = *(const f16x8*)(Ab + off);
                }
            if (next < 4 * nt) issue_half(next++);
            if (next < 4 * nt) issue_half(next++);
            asm volatile("s_barrier" ::: "memory");
            asm volatile("s_waitcnt lgkmcnt(0)" ::: "memory");
            __builtin_amdgcn_sched_barrier(0);
            __builtin_amdgcn_s_setprio(1);
            #pragma unroll
            for (int i = 0; i < 4; ++i)
                #pragma unroll
                for (int n = 0; n < 4; ++n)
                    #pragma unroll
                    for (int ks = 0; ks < 2; ++ks)
                        acc[4 * p + i][n] = __builtin_amdgcn_mfma_f32_16x16x32_f16(
                            af[i][ks], bf[n][ks], acc[4 * p + i][n], 0, 0, 0);
            __builtin_amdgcn_s_setprio(0);
            if (p == 1 && t + 1 < nt) {
                if (next >= 4 * t + 10) asm volatile("s_waitcnt vmcnt(4)" ::: "memory");
                else                    asm volatile("s_waitcnt vmcnt(0)" ::: "memory");
            }
            asm volatile("s_barrier" ::: "memory");
        }
    }

    f16* Cw = C;
    if (C2 != nullptr && col0 >= splitcol) { Cw = C2; col0 -= splitcol; }

    const int rbase = row0 + wr * 128 + (lane >> 4) * 4;
    const int cbase = col0 + wc * 64 + (lane & 15);
    #pragma unroll
    for (int m = 0; m < 8; ++m) {
        #pragma unroll
        for (int n = 0; n < 4; ++n) {
            const int col = cbase + n * 16;
            #pragma unroll
            for (int r = 0; r < 4; ++r)
                Cw[(size_t)(rbase + m * 16 + r) * ldc + col] = (f16)acc[m][n][r];
        }
    }
}

// ---------------------------------------------------------------------------
// FP16 MFMA GEMM, m97 double-buffer + XOR unit-swizzle (T2, both sides).
// Used for delta and out GEMMs.
// ---------------------------------------------------------------------------
template<int EPI, typename OUT_T>
__global__ __launch_bounds__(256)
void hgemm128(const f16* __restrict__ A, int lda,
              const f16* __restrict__ Bt, int ldb,
              OUT_T* __restrict__ C, int ldc,
              int K, const float* __restrict__ bias,
              OUT_T* __restrict__ C2, int splitcol)
{
    __shared__ __align__(16) f16 As[2][128 * 32];
    __shared__ __align__(16) f16 Bs[2][128 * 32];

    const int tid  = threadIdx.x;
    const int lane = tid & 63, wave = tid >> 6;
    const int wr = wave >> 1, wc = wave & 1;
    const int row0 = blockIdx.x * 128;
    int col0 = blockIdx.y * 128;

    const int lrow = lane >> 2;
    const int lcol = ((lane & 3) ^ ((lane >> 3) & 3)) * 8;
    const f16* Agw = A  + (size_t)(row0 + wave * 32 + lrow) * lda + lcol;
    const f16* Bgw = Bt + (size_t)(col0 + wave * 32 + lrow) * ldb + lcol;
    const int ldsbase = (wave * 32) * 32;   // elems

    const int frow = lane & 15;
    const int fk   = (((lane >> 4) ^ ((frow >> 1) & 3))) * 8;
    const int nt = K / 32;

    f32x4 acc[4][4] = {};

    #pragma unroll
    for (int r = 0; r < 2; ++r) {
        gload_lds16(Agw + (size_t)r * 16 * lda, &As[0][ldsbase + r * 16 * 32]);
        gload_lds16(Bgw + (size_t)r * 16 * ldb, &Bs[0][ldsbase + r * 16 * 32]);
    }

    int cur = 0;
    for (int kt = 0; kt < nt; ++kt) {
        __syncthreads();
        if (kt + 1 < nt) {
            const int k0 = (kt + 1) * 32;
            #pragma unroll
            for (int r = 0; r < 2; ++r) {
                gload_lds16(Agw + (size_t)r * 16 * lda + k0, &As[cur ^ 1][ldsbase + r * 16 * 32]);
                gload_lds16(Bgw + (size_t)r * 16 * ldb + k0, &Bs[cur ^ 1][ldsbase + r * 16 * 32]);
            }
        }
        f16x8 af[4], bf[4];
        #pragma unroll
        for (int m = 0; m < 4; ++m)
            af[m] = *(const f16x8*)&As[cur][(wr * 64 + m * 16 + frow) * 32 + fk];
        #pragma unroll
        for (int n = 0; n < 4; ++n)
            bf[n] = *(const f16x8*)&Bs[cur][(wc * 64 + n * 16 + frow) * 32 + fk];
        #pragma unroll
        for (int m = 0; m < 4; ++m)
            #pragma unroll
            for (int n = 0; n < 4; ++n)
                acc[m][n] = __builtin_amdgcn_mfma_f32_16x16x32_f16(af[m], bf[n], acc[m][n], 0, 0, 0);
        cur ^= 1;
    }

    OUT_T* Cw = C;
    if (C2 != nullptr && col0 >= splitcol) { Cw = C2; col0 -= splitcol; }

    const int rbase = row0 + wr * 64 + (lane >> 4) * 4;
    const int cbase = col0 + wc * 64 + (lane & 15);
    #pragma unroll
    for (int m = 0; m < 4; ++m) {
        #pragma unroll
        for (int n = 0; n < 4; ++n) {
            const int col = cbase + n * 16;
            #pragma unroll
            for (int r = 0; r < 4; ++r) {
                const int row = rbase + m * 16 + r;
                float tv = acc[m][n][r];
                if (EPI == 1) {
                    tv += bias[col];
                    tv = (tv > 20.f) ? tv : __logf(1.f + __expf(tv));
                }
                Cw[(size_t)row * ldc + col] = (OUT_T)tv;
            }
        }
    }
}

// ---------------------------------------------------------------------------
// Narrow-N GEMM for proj: part[sk] = uh[rows][kseg] @ WxpT^T, N=96, split-K=4.
// ---------------------------------------------------------------------------
__global__ __launch_bounds__(256)
void hgemm_n96(const f16* __restrict__ A,      // uh [MTOK][DINNER]
               const f16* __restrict__ Bt,     // WxpT [96][DINNER]
               float* __restrict__ part)       // [SPLITK][MTOK][96]
{
    __shared__ __align__(16) f16 As[128][40];
    __shared__ __align__(16) f16 Bs[96][40];

    const int tid = threadIdx.x, lane = tid & 63, wave = tid >> 6;
    const int row0 = blockIdx.x * 128;
    const int sk = blockIdx.y;
    const int kbase = sk * (DINNER / SPLITK);   // 512

    const int srow = tid >> 1, skoff = (tid & 1) * 16;
    const f16* Ag = A  + (size_t)(row0 + srow) * DINNER + kbase + skoff;
    const f16* Bg = Bt + (size_t)srow * DINNER + kbase + skoff;

    const int frow = lane & 15, fk = (lane >> 4) * 8;

    f32x4 acc[2][6] = {};

    for (int kk = 0; kk < DINNER / SPLITK; kk += 32) {
        const f16x8 a0 = *(const f16x8*)(Ag + kk);
        const f16x8 a1 = *(const f16x8*)(Ag + kk + 8);
        f16x8 b0 = {}, b1 = {};
        if (tid < 192) { b0 = *(const f16x8*)(Bg + kk); b1 = *(const f16x8*)(Bg + kk + 8); }
        __syncthreads();
        *(f16x8*)&As[srow][skoff]     = a0;
        *(f16x8*)&As[srow][skoff + 8] = a1;
        if (tid < 192) {
            *(f16x8*)&Bs[srow][skoff]     = b0;
            *(f16x8*)&Bs[srow][skoff + 8] = b1;
        }
        __syncthreads();

        f16x8 af[2], bf[6];
        #pragma unroll
        for (int m = 0; m < 2; ++m)
            af[m] = *(const f16x8*)&As[wave * 32 + m * 16 + frow][fk];
        #pragma unroll
        for (int n = 0; n < 6; ++n)
            bf[n] = *(const f16x8*)&Bs[n * 16 + frow][fk];
        #pragma unroll
        for (int m = 0; m < 2; ++m)
            #pragma unroll
            for (int n = 0; n < 6; ++n)
                acc[m][n] = __builtin_amdgcn_mfma_f32_16x16x32_f16(af[m], bf[n], acc[m][n], 0, 0, 0);
    }

    #pragma unroll
    for (int m = 0; m < 2; ++m)
        #pragma unroll
        for (int n = 0; n < 6; ++n) {
            const int col = n * 16 + (lane & 15);
            #pragma unroll
            for (int r = 0; r < 4; ++r) {
                const int row = row0 + wave * 32 + m * 16 + (lane >> 4) * 4 + r;
                part[((size_t)sk * MTOK + row) * 96 + col] = acc[m][n][r];
            }
        }
}

__global__ __launch_bounds__(256)
void reduce3(const float* __restrict__ part, float* __restrict__ proj,
             f16* __restrict__ projh)
{
    const int e = blockIdx.x * 256 + threadIdx.x;   // < NPROJ
    float s = 0.f;
    #pragma unroll
    for (int i = 0; i < SPLITK; ++i) s += part[(size_t)i * NPROJ + e];
    proj[e]  = s;
    projh[e] = (f16)s;
}

// ---------------------------------------------------------------------------
// Causal depthwise conv (D_CONV=4) + bias + SiLU, sliding-window.
// ---------------------------------------------------------------------------
__global__ __launch_bounds__(256)
void conv_silu_kernel(const f16* __restrict__ uph,
                      const float* __restrict__ cw, const float* __restrict__ cb,
                      f16* __restrict__ uh)
{
    const int mt  = blockIdx.x;          // 0 .. MTOK/8-1
    const int ml0 = mt * 8;
    const int l0  = ml0 & (LSEQ - 1);
    const int d   = threadIdx.x * 8;

    float w[8][4];
    #pragma unroll
    for (int c = 0; c < 8; ++c) {
        const float4 wv = *(const float4*)(cw + (size_t)(d + c) * 4);
        w[c][0] = wv.x; w[c][1] = wv.y; w[c][2] = wv.z; w[c][3] = wv.w;
    }
    float bias[8];
    {
        const float4 b0 = *(const float4*)(cb + d);
        const float4 b1 = *(const float4*)(cb + d + 4);
        bias[0] = b0.x; bias[1] = b0.y; bias[2] = b0.z; bias[3] = b0.w;
        bias[4] = b1.x; bias[5] = b1.y; bias[6] = b1.z; bias[7] = b1.w;
    }

    f16x8 r[11];
    if (l0 != 0) {
        #pragma unroll
        for (int i = 0; i < 11; ++i)
            r[i] = *(const f16x8*)(uph + (size_t)(ml0 - 3 + i) * DINNER + d);
    } else {
        r[0] = f16x8{}; r[1] = f16x8{}; r[2] = f16x8{};
        #pragma unroll
        for (int i = 3; i < 11; ++i)
            r[i] = *(const f16x8*)(uph + (size_t)(ml0 - 3 + i) * DINNER + d);
    }

    #pragma unroll
    for (int i = 0; i < 8; ++i) {
        f16x8 o;
        #pragma unroll
        for (int c = 0; c < 8; ++c) {
            float a = bias[c];
            #pragma unroll
            for (int j = 0; j < 4; ++j)
                a = fmaf((float)r[i + j][c], w[c][j], a);
            o[c] = (f16)silu_f(a);
        }
        *(f16x8*)(uh + (size_t)(ml0 + i) * DINNER + d) = o;
    }
}

// ---------------------------------------------------------------------------
// Chunked selective scan.  A-structure fast path (A[d][n] = (n+1)*A[d][0],
// true here: A = -[1..16]): exp(dt*A[n]) = e1^(n+1), power ladder depth ~4.
// B/C rows block-uniform -> scalar-pipe global loads; Sbuf stored f16.
// ---------------------------------------------------------------------------
__device__ __forceinline__ bool load_A(const float* __restrict__ A_log, int d,
                                       float* Av)
{
    #pragma unroll
    for (int n = 0; n < DSTATE; ++n)
        Av[n] = -__expf(A_log[(size_t)d * DSTATE + n]);
    bool p = true;
    #pragma unroll
    for (int n = 1; n < DSTATE; ++n) {
        const float r = Av[n] / Av[0];
        if (fabsf(r - (float)(n + 1)) > 1e-3f) p = false;
    }
    return p;
}

__global__ __launch_bounds__(256)
void scan_pass1(const f16* __restrict__ uh,
                const f16* __restrict__ deltah,    // [MTOK][DINNER] f16
                const float* __restrict__ proj,    // [MTOK][96], 64..95 = B,C
                const float* __restrict__ A_log,
                f16* __restrict__ Sbufh, float* __restrict__ sumdt)
{
    const int d = blockIdx.x * 256 + threadIdx.x;
    const int c = blockIdx.y;
    const int b = blockIdx.z;

    float Av[DSTATE];
    const bool pw = load_A(A_log, d, Av);
    const float Av0 = Av[0];

    const float* projb = proj + ((size_t)b * LSEQ + (size_t)c * CHUNK) * 96 + 64;

    float S[DSTATE];
    #pragma unroll
    for (int n = 0; n < DSTATE; ++n) S[n] = 0.f;
    float sdt = 0.f;

    const size_t tok0 = (size_t)b * LSEQ + (size_t)c * CHUNK;
    if (pw) {
        for (int l = 0; l < CHUNK; ++l) {
            const float* pr = projb + (size_t)l * 96;   // uniform address
            const float dt = (float)deltah[(tok0 + l) * DINNER + d];
            const float uu = (float)uh[(tok0 + l) * DINNER + d];
            sdt += dt;
            const float du = dt * uu;
            const float p1 = __expf(dt * Av0);
            const float p2 = p1 * p1;
            const float p3 = p2 * p1;
            const float p4 = p2 * p2;
            float m = 1.f;
            #pragma unroll
            for (int g = 0; g < 4; ++g) {
                const f32x4 bb = *(const f32x4*)(pr + g * 4);
                S[g*4+0] = fmaf(S[g*4+0], m * p1, du * bb[0]);
                S[g*4+1] = fmaf(S[g*4+1], m * p2, du * bb[1]);
                S[g*4+2] = fmaf(S[g*4+2], m * p3, du * bb[2]);
                S[g*4+3] = fmaf(S[g*4+3], m * p4, du * bb[3]);
                m *= p4;
            }
        }
    } else {
        for (int l = 0; l < CHUNK; ++l) {
            const float* pr = projb + (size_t)l * 96;
            const float dt = (float)deltah[(tok0 + l) * DINNER + d];
            const float uu = (float)uh[(tok0 + l) * DINNER + d];
            sdt += dt;
            const float du = dt * uu;
            #pragma unroll
            for (int n = 0; n < DSTATE; ++n)
                S[n] = fmaf(S[n], __expf(dt * Av[n]), du * pr[n]);
        }
    }

    const size_t base = (size_t)b * NCH + c;
    #pragma unroll
    for (int n = 0; n < DSTATE; ++n)
        Sbufh[(base * DSTATE + n) * DINNER + d] = (f16)S[n];
    sumdt[base * DINNER + d] = sdt;
}

// pass2: thread per (b, d, n) -- serial over chunks only.
__global__ __launch_bounds__(256)
void scan_pass2(const float* __restrict__ A_log,
                const float* __restrict__ sumdt,
                f16* __restrict__ Sbufh)
{
    const int d = blockIdx.x * 64 + (threadIdx.x & 63);
    const int n = blockIdx.y * 4 + (threadIdx.x >> 6);
    const int b = blockIdx.z;

    const float Avn = -__expf(A_log[(size_t)d * DSTATE + n]);

    float h = 0.f;
    for (int c = 0; c < NCH; ++c) {
        const size_t base = (size_t)b * NCH + c;
        const float sdt = sumdt[base * DINNER + d];
        const size_t idx = (base * DSTATE + n) * DINNER + d;
        const float tmp = (float)Sbufh[idx];
        Sbufh[idx] = (f16)h;
        h = fmaf(h, __expf(sdt * Avn), tmp);
    }
}

__global__ __launch_bounds__(256)
void scan_pass3(const f16* __restrict__ uh,
                const f16* __restrict__ deltah,
                const f16* __restrict__ zh,
                const float* __restrict__ proj,
                const float* __restrict__ A_log,
                const float* __restrict__ Dp,
                const f16* __restrict__ Sbufh,
                f16* __restrict__ ygh)
{
    const int d = blockIdx.x * 256 + threadIdx.x;
    const int c = blockIdx.y;
    const int b = blockIdx.z;

    float Av[DSTATE];
    const bool pw = load_A(A_log, d, Av);
    const float Av0 = Av[0];

    float h[DSTATE];
    const size_t base = (size_t)b * NCH + c;
    #pragma unroll
    for (int n = 0; n < DSTATE; ++n)
        h[n] = (float)Sbufh[(base * DSTATE + n) * DINNER + d];

    const float Dval = Dp[d];
    const float* projb = proj + ((size_t)b * LSEQ + (size_t)c * CHUNK) * 96 + 64;

    const size_t tok0 = (size_t)b * LSEQ + (size_t)c * CHUNK;
    for (int l = 0; l < CHUNK; ++l) {
        const float* pr = projb + (size_t)l * 96;   // uniform: B at +0, C at +16
        const size_t tok = tok0 + l;
        const float dt = (float)deltah[tok * DINNER + d];
        const float uu = (float)uh[tok * DINNER + d];
        const float zz = (float)zh[tok * DINNER + d];
        const float du = dt * uu;
        float y = 0.f;
        if (pw) {
            const float p1 = __expf(dt * Av0);
            const float p2 = p1 * p1;
            const float p3 = p2 * p1;
            const float p4 = p2 * p2;
            float m = 1.f;
            #pragma unroll
            for (int g = 0; g < 4; ++g) {
                const f32x4 bb = *(const f32x4*)(pr + g * 4);
                const f32x4 cc = *(const f32x4*)(pr + 16 + g * 4);
                h[g*4+0] = fmaf(h[g*4+0], m * p1, du * bb[0]);
                h[g*4+1] = fmaf(h[g*4+1], m * p2, du * bb[1]);
                h[g*4+2] = fmaf(h[g*4+2], m * p3, du * bb[2]);
                h[g*4+3] = fmaf(h[g*4+3], m * p4, du * bb[3]);
                y = fmaf(h[g*4+0], cc[0], y);
                y = fmaf(h[g*4+1], cc[1], y);
                y = fmaf(h[g*4+2], cc[2], y);
                y = fmaf(h[g*4+3], cc[3], y);
                m *= p4;
            }
        } else {
            #pragma unroll
            for (int n = 0; n < DSTATE; ++n) {
                h[n] = fmaf(h[n], __expf(dt * Av[n]), du * pr[n]);
                y = fmaf(h[n], pr[16 + n], y);
            }
        }
        const float yt = fmaf(uu, Dval, y);
        ygh[tok * DINNER + d] = (f16)(yt * silu_f(zz));
    }
}

// ---------------------------------------------------------------------------
extern "C" void kernel_launch(void* const* d_in, const int* in_sizes, int n_in,
                              void* d_out, int out_size, void* d_ws, size_t ws_size,
                              hipStream_t stream)
{
    const float* x     = (const float*)d_in[0];
    const float* W_in  = (const float*)d_in[1];
    const float* cw    = (const float*)d_in[2];
    const float* cb    = (const float*)d_in[3];
    const float* W_xp  = (const float*)d_in[4];
    const float* W_dt  = (const float*)d_in[5];
    const float* b_dt  = (const float*)d_in[6];
    const float* A_log = (const float*)d_in[7];
    const float* Dp    = (const float*)d_in[8];
    const float* W_out = (const float*)d_in[9];
    float* out = (float*)d_out;

    // ---- workspace layout ----
    float* updelta = (float*)d_ws;                   // [MTOK][DINNER] f32 region: uph(f16) -> deltah(f16)
    f16*   zh      = (f16*)(updelta + (size_t)MTOK * DINNER);   // [MTOK][DINNER] f16
    f16*   uh      = zh + (size_t)MTOK * DINNER;     // [MTOK][DINNER] f16 (xh alias at base)
    float* proj    = (float*)(uh + (size_t)MTOK * DINNER);      // [MTOK][96] f32
    f16*   projh   = (f16*)(proj + NPROJ);           // [MTOK][96] f16
    f16*   Sbufh   = (f16*)(projh + NPROJ);          // [B][NCH][16][DINNER] f16
    float* sumdt   = (float*)(Sbufh + (size_t)NBATCH * NCH * DSTATE * DINNER * 2);
    f16*   WxpT    = (f16*)(sumdt + (size_t)NBATCH * NCH * DINNER);  // [96][DINNER]
    f16*   WdtT    = WxpT + (size_t)96 * DINNER;     // [DINNER][64]
    f16*   WoutT   = WdtT + (size_t)DINNER * DTRANK; // [DMODEL][DINNER]
    f16*   big     = WoutT + (size_t)DMODEL * DINNER;// 16.78M f16 alias region
    f16*   WinT    = big;                            // [NXZ][DMODEL] (phase 1)
    float* part3   = (float*)(big + (size_t)NXZ * DMODEL);  // [SPLITK][MTOK][96] (phase 2)
    f16*   ygh     = big;                            // [MTOK][DINNER] (phase 3)
    f16*   xh      = uh;                             // [MTOK][DMODEL] (pre-conv alias)
    f16*   uph     = (f16*)updelta;                  // [MTOK][DINNER] f16 (dead before delta)
    f16*   deltah  = (f16*)updelta;                  // [MTOK][DINNER] f16 (over uph)

    // 1) all input prep in one dispatch
    prep_all<<<14656, 256, 0, stream>>>(x, xh, W_in, WinT, W_xp, WxpT,
                                        W_dt, WdtT, W_out, WoutT);

    // 2) GEMM1: [u_pre | z] = x @ W_in, 256x256 2-phase pipelined, split outputs
    hgemm256p<<<dim3(32, 16), 512, 0, stream>>>(
        xh, DMODEL, WinT, DMODEL, uph, DINNER, DMODEL, zh, DINNER);

    // 3) conv + silu -> uh f16   (clobbers xh)
    conv_silu_kernel<<<MTOK / 8, 256, 0, stream>>>(uph, cw, cb, uh);

    // 4) proj = u @ W_xproj  (split-K=4, N=96) + reduce
    hgemm_n96<<<dim3(64, SPLITK), 256, 0, stream>>>(uh, WxpT, part3);
    reduce3<<<NPROJ / 256, 256, 0, stream>>>(part3, proj, projh);

    // 5) deltah = softplus(proj[:, :64] @ W_dt + b_dt) f16 (uph dead)
    hgemm128<1, f16><<<dim3(64, 16), 256, 0, stream>>>(
        projh, 96, WdtT, DTRANK, deltah, DINNER, DTRANK, b_dt, nullptr, 0);

    // 6) chunked scan + skip + gate -> ygh f16 (clobbers WinT/part3)
    scan_pass1<<<dim3(DINNER / 256, NCH, NBATCH), 256, 0, stream>>>(
        uh, deltah, proj, A_log, Sbufh, sumdt);
    scan_pass2<<<dim3(DINNER / 64, DSTATE / 4, NBATCH), 256, 0, stream>>>(
        A_log, sumdt, Sbufh);
    scan_pass3<<<dim3(DINNER / 256, NCH, NBATCH), 256, 0, stream>>>(
        uh, deltah, zh, proj, A_log, Dp, Sbufh, ygh);

    // 7) out = yg @ W_out
    hgemm128<0, float><<<dim3(64, 8), 256, 0, stream>>>(
        ygh, DINNER, WoutT, DINNER, out, DMODEL, DINNER, nullptr, nullptr, 0);
}